// Round 4
// baseline (180.213 us; speedup 1.0000x reference)
//
#include <hip/hip_runtime.h>
#include <hip/hip_bf16.h>
#include <stdint.h>
#include <math.h>

// Problem dims
#define B_    1024
#define LAT   64
#define FCON  256
#define IN_SZ 320          // LAT + FCON
#define HID   512
#define E_    8
#define GH    64
#define INTER 576          // LAT + HID
#define OUT_SZ 512
#define NTOT  4096         // E_ * 512
#define KI0   10           // IN_SZ/32
#define KI12  18           // INTER/32

typedef __attribute__((ext_vector_type(8))) __bf16 bf16x8;
typedef __attribute__((ext_vector_type(4))) __bf16 bf16x4;
typedef __attribute__((ext_vector_type(4))) float  f32x4;

__device__ __forceinline__ float elu_f(float x) { return x > 0.f ? x : expf(x) - 1.f; }
__device__ __forceinline__ __bf16 to_bf16(float f) {
    __hip_bfloat16 h = __float2bfloat16(f);
    return *reinterpret_cast<__bf16*>(&h);
}

// ---------------------------------------------------------------------------
// Fragment layout (mfma_f32_16x16x32_bf16 A/B operand, m89-verified):
//   frag(t0,k0)[lane][j] = X[t0 + (lane&15)][k0 + (lane>>4)*8 + j],  j=0..7
// Packed storage: buf[(tile_idx*KI + ki)*64 + lane] : bf16x8 (16 B/lane).
// ---------------------------------------------------------------------------

// ----- fused prep kernel: zcpack + 3x wpack + gate in ONE dispatch ---------
// block roles by blockIdx.x:
//   [0,160)       zcpack   (640 wave-fragments)
//   [160,800)     wpack w0 (KI0*64  = 640 block-equivs)
//   [800,1952)    wpack w1 (KI12*64 = 1152)
//   [1952,3104)   wpack w2
//   [3104,3360)   gate     (256 blocks x 4 rows)
#define PREP_ZC   160
#define PREP_W0   (PREP_ZC + KI0 * 64)      // 800
#define PREP_W1   (PREP_W0 + KI12 * 64)     // 1952
#define PREP_W2   (PREP_W1 + KI12 * 64)     // 3104
#define PREP_ALL  (PREP_W2 + 256)           // 3360

__device__ __forceinline__ void do_zcpack(
    int bx, const float* __restrict__ z, const float* __restrict__ c,
    bf16x8* __restrict__ Ap0, bf16x8* __restrict__ Ap1, bf16x8* __restrict__ Ap2)
{
    const int wid  = bx * 4 + (threadIdx.x >> 6);
    const int lane = threadIdx.x & 63, q = lane >> 4, r = lane & 15;
    bf16x8 v;
    if (wid < 128) {                       // z fragment: mi in [0,64), ki in {0,1}
        const int mi = wid >> 1, ki = wid & 1;
        const float* src = z + (size_t)(mi * 16 + r) * LAT + ki * 32 + q * 8;
        const f32x4 lo = *(const f32x4*)src, hi = *(const f32x4*)(src + 4);
#pragma unroll
        for (int j = 0; j < 4; j++) { v[j] = to_bf16(lo[j]); v[j + 4] = to_bf16(hi[j]); }
        Ap0[((size_t)mi * KI0  + ki) * 64 + lane] = v;
        Ap1[((size_t)mi * KI12 + ki) * 64 + lane] = v;
        Ap2[((size_t)mi * KI12 + ki) * 64 + lane] = v;
    } else {                               // c fragment: ki in [2,10)
        const int cid = wid - 128;
        const int mi = cid >> 3, ki = 2 + (cid & 7);
        const float* src = c + (size_t)(mi * 16 + r) * FCON + (ki - 2) * 32 + q * 8;
        const f32x4 lo = *(const f32x4*)src, hi = *(const f32x4*)(src + 4);
#pragma unroll
        for (int j = 0; j < 4; j++) { v[j] = to_bf16(lo[j]); v[j + 4] = to_bf16(hi[j]); }
        Ap0[((size_t)mi * KI0 + ki) * 64 + lane] = v;
    }
}

__device__ __forceinline__ void do_wpack(
    int f, const float* __restrict__ w, bf16x8* __restrict__ Wp, int KI)
{
    const int ki = f % KI;
    const int ni = (f / KI) * 4 + (threadIdx.x >> 6);
    const int lane = threadIdx.x & 63, q = lane >> 4, r = lane & 15;
    const int n = ni * 16 + r, e = n >> 9, o = n & 511;
    const int K = KI * 32;
    const float* src = w + (size_t)e * K * 512 + (size_t)(ki * 32 + q * 8) * 512 + o;
    bf16x8 v;
#pragma unroll
    for (int j = 0; j < 8; j++) v[j] = to_bf16(src[(size_t)j * 512]);
    Wp[((size_t)ni * KI + ki) * 64 + lane] = v;
}

__global__ __launch_bounds__(256) void prep_kernel(
    const float* __restrict__ z, const float* __restrict__ c,
    const float* __restrict__ w0, const float* __restrict__ w1,
    const float* __restrict__ w2,
    const float* __restrict__ gw1, const float* __restrict__ gb1,
    const float* __restrict__ gw2, const float* __restrict__ gb2,
    const float* __restrict__ gw3, const float* __restrict__ gb3,
    bf16x8* __restrict__ Ap0, bf16x8* __restrict__ Ap1, bf16x8* __restrict__ Ap2,
    bf16x8* __restrict__ Wp0, bf16x8* __restrict__ Wp1, bf16x8* __restrict__ Wp2,
    float* __restrict__ coeff)
{
    const int bx = blockIdx.x;
    if (bx < PREP_ZC) {
        do_zcpack(bx, z, c, Ap0, Ap1, Ap2);
    } else if (bx < PREP_W0) {
        do_wpack(bx - PREP_ZC, w0, Wp0, KI0);
    } else if (bx < PREP_W1) {
        do_wpack(bx - PREP_W0, w1, Wp1, KI12);
    } else if (bx < PREP_W2) {
        do_wpack(bx - PREP_W1, w2, Wp2, KI12);
    } else {
        // ----- gate: coeff = softmax(elu(elu(x@gw1+gb1)@gw2+gb2)@gw3+gb3) ---
        __shared__ float h[4][GH];
        __shared__ float lg[4][E_];
        const int lane = threadIdx.x & 63, wave = threadIdx.x >> 6;
        const int row = (bx - PREP_W2) * 4 + wave;
        const float* zr = z + (size_t)row * LAT;
        const float* cr = c + (size_t)row * FCON;

        float a1 = gb1[lane];
        for (int i = 0; i < LAT; i++)  a1 = fmaf(zr[i], gw1[i * GH + lane], a1);
        for (int i = 0; i < FCON; i++) a1 = fmaf(cr[i], gw1[(LAT + i) * GH + lane], a1);
        h[wave][lane] = elu_f(a1);
        __syncthreads();

        float a2 = gb2[lane];
        for (int i = 0; i < GH; i++) a2 = fmaf(h[wave][i], gw2[i * GH + lane], a2);
        a2 = elu_f(a2);
        __syncthreads();
        h[wave][lane] = a2;
        __syncthreads();

        if (lane < E_) {
            float a3 = gb3[lane];
            for (int i = 0; i < GH; i++) a3 = fmaf(h[wave][i], gw3[i * E_ + lane], a3);
            lg[wave][lane] = a3;
        }
        __syncthreads();
        if (lane < E_) {
            float mx = lg[wave][0];
            for (int i = 1; i < E_; i++) mx = fmaxf(mx, lg[wave][i]);
            float s = 0.f;
            for (int i = 0; i < E_; i++) s += expf(lg[wave][i] - mx);
            coeff[(size_t)row * E_ + lane] = expf(lg[wave][lane] - mx) / s;
        }
    }
}

// ---------------------------------------------------------------------------
// Barrier-free fragment-direct GEMM: Y[1024, 4096] f32 = A * W^T from packed
// fragments. No LDS, no __syncthreads. Block 64m x 128n, wave 32m x 64n.
// grid (32, 16) = 512 blocks -> 2 blocks/CU.
// ---------------------------------------------------------------------------
template<int KI>
__global__ __launch_bounds__(256, 2) void gemm_frag(
    const bf16x8* __restrict__ Ap, const bf16x8* __restrict__ Wp,
    float* __restrict__ Y)
{
    const int t = threadIdx.x;
    const int lane = t & 63, wave = t >> 6;
    const int n0 = blockIdx.x * 128;
    const int m0 = blockIdx.y * 64;
    const int mw = (wave >> 1) * 32, nw = (wave & 1) * 64;
    const int q = lane >> 4, r = lane & 15;
    const int miB = (m0 + mw) >> 4;
    const int niB = (n0 + nw) >> 4;

    const bf16x8* aBase = Ap + (size_t)miB * KI * 64 + lane;
    const bf16x8* bBase = Wp + (size_t)niB * KI * 64 + lane;

    f32x4 acc[2][4];
#pragma unroll
    for (int i = 0; i < 2; i++)
#pragma unroll
        for (int j = 0; j < 4; j++) acc[i][j] = (f32x4){0.f, 0.f, 0.f, 0.f};

#pragma unroll
    for (int ki = 0; ki < KI; ++ki) {
        bf16x8 af[2], bf[4];
#pragma unroll
        for (int im = 0; im < 2; im++) af[im] = aBase[((size_t)im * KI + ki) * 64];
#pragma unroll
        for (int in = 0; in < 4; in++) bf[in] = bBase[((size_t)in * KI + ki) * 64];
#pragma unroll
        for (int im = 0; im < 2; im++)
#pragma unroll
            for (int in = 0; in < 4; in++)
                acc[im][in] = __builtin_amdgcn_mfma_f32_16x16x32_bf16(
                    af[im], bf[in], acc[im][in], 0, 0, 0);
    }

    // D layout: col = lane&15, row = (lane>>4)*4 + reg  [m89-verified]
#pragma unroll
    for (int im = 0; im < 2; im++)
#pragma unroll
        for (int in = 0; in < 4; in++) {
            const int n = n0 + nw + in * 16 + r;
#pragma unroll
            for (int v = 0; v < 4; v++) {
                const int m = m0 + mw + im * 16 + q * 4 + v;
                Y[(size_t)m * NTOT + n] = acc[im][in][v];
            }
        }
}

// ---------------------------------------------------------------------------
// Expert reduce: s[b,o] = sum_e coeff[b,e] * (Y[b,e*512+o] + bias[e,o]).
// FINAL=0: elu(s) -> packed A-fragments of the next layer (k = 64+o, KI12).
// FINAL=1: s -> f32 d_out.
// ---------------------------------------------------------------------------
template<int FINAL>
__global__ __launch_bounds__(256) void reduce_kernel(
    const float* __restrict__ Y, const float* __restrict__ coeff,
    const float* __restrict__ bias,
    bf16x4* __restrict__ ApN, float* __restrict__ fout)
{
    const int idx = blockIdx.x * 256 + threadIdx.x;   // B_*128 exactly
    const int b = idx >> 7;
    const int o = (idx & 127) * 4;
    const float* cb = coeff + (size_t)b * E_;
    f32x4 s = (f32x4){0.f, 0.f, 0.f, 0.f};
#pragma unroll
    for (int e = 0; e < E_; e++) {
        const float ce = cb[e];
        const f32x4 y  = *(const f32x4*)(Y + (size_t)b * NTOT + e * 512 + o);
        const f32x4 bs = *(const f32x4*)(bias + (size_t)e * 512 + o);
#pragma unroll
        for (int v = 0; v < 4; v++) s[v] += ce * (y[v] + bs[v]);
    }
    if (FINAL) {
        *(f32x4*)(fout + (size_t)b * OUT_SZ + o) = s;
    } else {
#pragma unroll
        for (int v = 0; v < 4; v++) s[v] = elu_f(s[v]);
        bf16x4 vq;
#pragma unroll
        for (int v = 0; v < 4; v++) vq[v] = to_bf16(s[v]);
        const int k  = LAT + o;
        const int mi = b >> 4, r = b & 15;
        const int ki = k >> 5, kq = (k & 31) >> 3, jb = k & 7;   // jb in {0,4}
        ApN[(((size_t)mi * KI12 + ki) * 64 + kq * 16 + r) * 2 + (jb >> 2)] = vq;
    }
}

// ---------------------------------------------------------------------------
static inline size_t align256(size_t x) { return (x + 255) & ~(size_t)255; }

extern "C" void kernel_launch(void* const* d_in, const int* in_sizes, int n_in,
                              void* d_out, int out_size, void* d_ws, size_t ws_size,
                              hipStream_t stream)
{
    const float* z   = (const float*)d_in[0];
    const float* c   = (const float*)d_in[1];
    const float* w0  = (const float*)d_in[2];
    const float* b0  = (const float*)d_in[3];
    const float* w1  = (const float*)d_in[4];
    const float* b1  = (const float*)d_in[5];
    const float* w2  = (const float*)d_in[6];
    const float* b2  = (const float*)d_in[7];
    const float* gw1 = (const float*)d_in[8];
    const float* gb1 = (const float*)d_in[9];
    const float* gw2 = (const float*)d_in[10];
    const float* gb2 = (const float*)d_in[11];
    const float* gw3 = (const float*)d_in[12];
    const float* gb3 = (const float*)d_in[13];
    float* out = (float*)d_out;

    uint8_t* p = (uint8_t*)d_ws;
    bf16x8* Wp0 = (bf16x8*)p; p += align256((size_t)NTOT * IN_SZ * 2);
    bf16x8* Wp1 = (bf16x8*)p; p += align256((size_t)NTOT * INTER * 2);
    bf16x8* Wp2 = (bf16x8*)p; p += align256((size_t)NTOT * INTER * 2);
    bf16x8* Ap0 = (bf16x8*)p; p += align256((size_t)B_ * IN_SZ * 2);
    bf16x8* Ap1 = (bf16x8*)p; p += align256((size_t)B_ * INTER * 2);
    bf16x8* Ap2 = (bf16x8*)p; p += align256((size_t)B_ * INTER * 2);
    float* coeff = (float*)p; p += align256((size_t)B_ * E_ * 4);
    float* Y     = (float*)p; p += align256((size_t)B_ * NTOT * 4);

    // 1) fused prep: packs + gate (1 dispatch instead of 5)
    prep_kernel<<<PREP_ALL, 256, 0, stream>>>(
        z, c, w0, w1, w2, gw1, gb1, gw2, gb2, gw3, gb3,
        Ap0, Ap1, Ap2, Wp0, Wp1, Wp2, coeff);

    // 2) layer 0
    gemm_frag<KI0><<<dim3(32, 16), 256, 0, stream>>>(Ap0, Wp0, Y);
    reduce_kernel<0><<<512, 256, 0, stream>>>(Y, coeff, b0, (bf16x4*)Ap1, nullptr);
    // 3) layer 1
    gemm_frag<KI12><<<dim3(32, 16), 256, 0, stream>>>(Ap1, Wp1, Y);
    reduce_kernel<0><<<512, 256, 0, stream>>>(Y, coeff, b1, (bf16x4*)Ap2, nullptr);
    // 4) layer 2 -> d_out (f32, no act)
    gemm_frag<KI12><<<dim3(32, 16), 256, 0, stream>>>(Ap2, Wp2, Y);
    reduce_kernel<1><<<512, 256, 0, stream>>>(Y, coeff, b2, nullptr, out);
}

// Round 6
// 165.928 us; speedup vs baseline: 1.0861x; 1.0861x over previous
//
#include <hip/hip_runtime.h>
#include <hip/hip_bf16.h>
#include <stdint.h>
#include <math.h>

// Problem dims
#define B_    1024
#define LAT   64
#define FCON  256
#define IN_SZ 320          // LAT + FCON
#define HID   512
#define E_    8
#define GH    64
#define INTER 576          // LAT + HID
#define OUT_SZ 512
#define NTOT  4096         // E_ * 512
#define KI0   10           // IN_SZ/32
#define KI12  18           // INTER/32

typedef __attribute__((ext_vector_type(8))) __bf16 bf16x8;
typedef __attribute__((ext_vector_type(4))) float  f32x4;

__device__ __forceinline__ float elu_f(float x) { return x > 0.f ? x : expf(x) - 1.f; }
__device__ __forceinline__ __bf16 to_bf16(float f) {
    __hip_bfloat16 h = __float2bfloat16(f);
    return *reinterpret_cast<__bf16*>(&h);
}

// ---------------------------------------------------------------------------
// Fragment layout (mfma_f32_16x16x32_bf16 A/B operand, m89-verified):
//   frag(t0,k0)[lane][j] = X[t0 + (lane&15)][k0 + (lane>>4)*8 + j],  j=0..7
// Packed storage: buf[(tile_idx*KI + ki)*64 + lane] : bf16x8 (16 B/lane).
// ---------------------------------------------------------------------------

// ----- fused prep kernel: zcpack + 3x wpack + gate in ONE dispatch ---------
#define PREP_ZC   160
#define PREP_W0   (PREP_ZC + KI0 * 64)      // 800
#define PREP_W1   (PREP_W0 + KI12 * 64)     // 1952
#define PREP_W2   (PREP_W1 + KI12 * 64)     // 3104
#define PREP_ALL  (PREP_W2 + 256)           // 3360

__device__ __forceinline__ void do_zcpack(
    int bx, const float* __restrict__ z, const float* __restrict__ c,
    bf16x8* __restrict__ Ap0, bf16x8* __restrict__ Ap1, bf16x8* __restrict__ Ap2)
{
    const int wid  = bx * 4 + (threadIdx.x >> 6);
    const int lane = threadIdx.x & 63, q = lane >> 4, r = lane & 15;
    bf16x8 v;
    if (wid < 128) {                       // z fragment: mi in [0,64), ki in {0,1}
        const int mi = wid >> 1, ki = wid & 1;
        const float* src = z + (size_t)(mi * 16 + r) * LAT + ki * 32 + q * 8;
        const f32x4 lo = *(const f32x4*)src, hi = *(const f32x4*)(src + 4);
#pragma unroll
        for (int j = 0; j < 4; j++) { v[j] = to_bf16(lo[j]); v[j + 4] = to_bf16(hi[j]); }
        Ap0[((size_t)mi * KI0  + ki) * 64 + lane] = v;
        Ap1[((size_t)mi * KI12 + ki) * 64 + lane] = v;
        Ap2[((size_t)mi * KI12 + ki) * 64 + lane] = v;
    } else {                               // c fragment: ki in [2,10)
        const int cid = wid - 128;
        const int mi = cid >> 3, ki = 2 + (cid & 7);
        const float* src = c + (size_t)(mi * 16 + r) * FCON + (ki - 2) * 32 + q * 8;
        const f32x4 lo = *(const f32x4*)src, hi = *(const f32x4*)(src + 4);
#pragma unroll
        for (int j = 0; j < 4; j++) { v[j] = to_bf16(lo[j]); v[j + 4] = to_bf16(hi[j]); }
        Ap0[((size_t)mi * KI0 + ki) * 64 + lane] = v;
    }
}

__device__ __forceinline__ void do_wpack(
    int f, const float* __restrict__ w, bf16x8* __restrict__ Wp, int KI)
{
    const int ki = f % KI;
    const int ni = (f / KI) * 4 + (threadIdx.x >> 6);
    const int lane = threadIdx.x & 63, q = lane >> 4, r = lane & 15;
    const int n = ni * 16 + r, e = n >> 9, o = n & 511;
    const int K = KI * 32;
    const float* src = w + (size_t)e * K * 512 + (size_t)(ki * 32 + q * 8) * 512 + o;
    bf16x8 v;
#pragma unroll
    for (int j = 0; j < 8; j++) v[j] = to_bf16(src[(size_t)j * 512]);
    Wp[((size_t)ni * KI + ki) * 64 + lane] = v;
}

__global__ __launch_bounds__(256) void prep_kernel(
    const float* __restrict__ z, const float* __restrict__ c,
    const float* __restrict__ w0, const float* __restrict__ w1,
    const float* __restrict__ w2,
    const float* __restrict__ gw1, const float* __restrict__ gb1,
    const float* __restrict__ gw2, const float* __restrict__ gb2,
    const float* __restrict__ gw3, const float* __restrict__ gb3,
    bf16x8* __restrict__ Ap0, bf16x8* __restrict__ Ap1, bf16x8* __restrict__ Ap2,
    bf16x8* __restrict__ Wp0, bf16x8* __restrict__ Wp1, bf16x8* __restrict__ Wp2,
    float* __restrict__ coeff)
{
    const int bx = blockIdx.x;
    if (bx < PREP_ZC) {
        do_zcpack(bx, z, c, Ap0, Ap1, Ap2);
    } else if (bx < PREP_W0) {
        do_wpack(bx - PREP_ZC, w0, Wp0, KI0);
    } else if (bx < PREP_W1) {
        do_wpack(bx - PREP_W0, w1, Wp1, KI12);
    } else if (bx < PREP_W2) {
        do_wpack(bx - PREP_W1, w2, Wp2, KI12);
    } else {
        // ----- gate: coeff = softmax(elu(elu(x@gw1+gb1)@gw2+gb2)@gw3+gb3) ---
        __shared__ float h[4][GH];
        __shared__ float lg[4][E_];
        const int lane = threadIdx.x & 63, wave = threadIdx.x >> 6;
        const int row = (bx - PREP_W2) * 4 + wave;
        const float* zr = z + (size_t)row * LAT;
        const float* cr = c + (size_t)row * FCON;

        float a1 = gb1[lane];
        for (int i = 0; i < LAT; i++)  a1 = fmaf(zr[i], gw1[i * GH + lane], a1);
        for (int i = 0; i < FCON; i++) a1 = fmaf(cr[i], gw1[(LAT + i) * GH + lane], a1);
        h[wave][lane] = elu_f(a1);
        __syncthreads();

        float a2 = gb2[lane];
        for (int i = 0; i < GH; i++) a2 = fmaf(h[wave][i], gw2[i * GH + lane], a2);
        a2 = elu_f(a2);
        __syncthreads();
        h[wave][lane] = a2;
        __syncthreads();

        if (lane < E_) {
            float a3 = gb3[lane];
            for (int i = 0; i < GH; i++) a3 = fmaf(h[wave][i], gw3[i * E_ + lane], a3);
            lg[wave][lane] = a3;
        }
        __syncthreads();
        if (lane < E_) {
            float mx = lg[wave][0];
            for (int i = 1; i < E_; i++) mx = fmaxf(mx, lg[wave][i]);
            float s = 0.f;
            for (int i = 0; i < E_; i++) s += expf(lg[wave][i] - mx);
            coeff[(size_t)row * E_ + lane] = expf(lg[wave][lane] - mx) / s;
        }
    }
}

// ---------------------------------------------------------------------------
// Fused layer kernel: GEMM + expert-reduce in one pass, no Y buffer.
// Block = 64m x (8 experts x 16 o-cols). Wave w = rows m0+w*16..+15, all 8
// expert-fragments in-register (acc[e], 32 VGPR). Epilogue does
// s = sum_e coeff[m,e]*(acc[e]+bias[e,o]) per lane-row, then ELU+frag-pack
// (layers 0,1) or f32 store (layer 2). grid (32 o-tiles, 16 m-tiles).
// ---------------------------------------------------------------------------
template<int KI, int FINAL>
__global__ __launch_bounds__(256, 2) void layer_kernel(
    const bf16x8* __restrict__ Ap, const bf16x8* __restrict__ Wp,
    const float* __restrict__ coeff, const float* __restrict__ bias,
    __bf16* __restrict__ ApN, float* __restrict__ fout)
{
    const int lane = threadIdx.x & 63, w = threadIdx.x >> 6;
    const int q = lane >> 4, r = lane & 15;
    const int o0 = blockIdx.x * 16;
    const int m0 = blockIdx.y * 64;
    const int mi = (m0 >> 4) + w;          // row-tile index for this wave
    const int nt = o0 >> 4;                // o-tile index within expert

    const bf16x8* aBase = Ap + (size_t)mi * KI * 64 + lane;
    const bf16x8* bBase = Wp + (size_t)nt * KI * 64 + lane;  // + e*(32*KI*64)

    f32x4 acc[E_];
#pragma unroll
    for (int e = 0; e < E_; e++) acc[e] = (f32x4){0.f, 0.f, 0.f, 0.f};

#pragma unroll
    for (int ki = 0; ki < KI; ++ki) {
        const bf16x8 af = aBase[(size_t)ki * 64];
        bf16x8 bf[E_];
#pragma unroll
        for (int e = 0; e < E_; e++)
            bf[e] = bBase[((size_t)e * 32 * KI + ki) * 64];
#pragma unroll
        for (int e = 0; e < E_; e++)
            acc[e] = __builtin_amdgcn_mfma_f32_16x16x32_bf16(af, bf[e], acc[e], 0, 0, 0);
    }

    // bias[e, o0+r]
    float be[E_];
#pragma unroll
    for (int e = 0; e < E_; e++) be[e] = bias[(size_t)e * 512 + o0 + r];

    // D layout: col(o) = lane&15, row(m) = q*4 + v  [m89-verified]
#pragma unroll
    for (int v = 0; v < 4; v++) {
        const int row = m0 + w * 16 + q * 4 + v;
        const float* cr = coeff + (size_t)row * E_;
        const f32x4 clo = *(const f32x4*)cr, chi = *(const f32x4*)(cr + 4);
        float s = 0.f;
#pragma unroll
        for (int e = 0; e < 4; e++) s += clo[e] * (acc[e][v] + be[e]);
#pragma unroll
        for (int e = 0; e < 4; e++) s += chi[e] * (acc[4 + e][v] + be[4 + e]);
        if (FINAL) {
            fout[(size_t)row * OUT_SZ + o0 + r] = s;
        } else {
            const float h = elu_f(s);
            const int k  = LAT + o0 + r;           // 64..575
            const int ki2 = k >> 5, kq2 = (k & 31) >> 3, jb2 = k & 7;
            ApN[(((size_t)mi * KI12 + ki2) * 64 + kq2 * 16 + (q * 4 + v)) * 8 + jb2] =
                to_bf16(h);
        }
    }
}

// ---------------------------------------------------------------------------
static inline size_t align256(size_t x) { return (x + 255) & ~(size_t)255; }

extern "C" void kernel_launch(void* const* d_in, const int* in_sizes, int n_in,
                              void* d_out, int out_size, void* d_ws, size_t ws_size,
                              hipStream_t stream)
{
    const float* z   = (const float*)d_in[0];
    const float* c   = (const float*)d_in[1];
    const float* w0  = (const float*)d_in[2];
    const float* b0  = (const float*)d_in[3];
    const float* w1  = (const float*)d_in[4];
    const float* b1  = (const float*)d_in[5];
    const float* w2  = (const float*)d_in[6];
    const float* b2  = (const float*)d_in[7];
    const float* gw1 = (const float*)d_in[8];
    const float* gb1 = (const float*)d_in[9];
    const float* gw2 = (const float*)d_in[10];
    const float* gb2 = (const float*)d_in[11];
    const float* gw3 = (const float*)d_in[12];
    const float* gb3 = (const float*)d_in[13];
    float* out = (float*)d_out;

    uint8_t* p = (uint8_t*)d_ws;
    bf16x8* Wp0 = (bf16x8*)p; p += align256((size_t)NTOT * IN_SZ * 2);
    bf16x8* Wp1 = (bf16x8*)p; p += align256((size_t)NTOT * INTER * 2);
    bf16x8* Wp2 = (bf16x8*)p; p += align256((size_t)NTOT * INTER * 2);
    bf16x8* Ap0 = (bf16x8*)p; p += align256((size_t)B_ * IN_SZ * 2);
    bf16x8* Ap1 = (bf16x8*)p; p += align256((size_t)B_ * INTER * 2);
    bf16x8* Ap2 = (bf16x8*)p; p += align256((size_t)B_ * INTER * 2);
    float* coeff = (float*)p; p += align256((size_t)B_ * E_ * 4);

    // 1) fused prep: packs + gate (verified in R4)
    prep_kernel<<<PREP_ALL, 256, 0, stream>>>(
        z, c, w0, w1, w2, gw1, gb1, gw2, gb2, gw3, gb3,
        Ap0, Ap1, Ap2, Wp0, Wp1, Wp2, coeff);

    // 2) three fused GEMM+reduce layers (no Y materialization)
    layer_kernel<KI0, 0><<<dim3(32, 16), 256, 0, stream>>>(
        Ap0, Wp0, coeff, b0, (__bf16*)Ap1, nullptr);
    layer_kernel<KI12, 0><<<dim3(32, 16), 256, 0, stream>>>(
        Ap1, Wp1, coeff, b1, (__bf16*)Ap2, nullptr);
    layer_kernel<KI12, 1><<<dim3(32, 16), 256, 0, stream>>>(
        Ap2, Wp2, coeff, b2, nullptr, out);
}

// Round 7
// 156.614 us; speedup vs baseline: 1.1507x; 1.0595x over previous
//
#include <hip/hip_runtime.h>
#include <hip/hip_bf16.h>
#include <stdint.h>
#include <math.h>

// Problem dims
#define B_    1024
#define LAT   64
#define FCON  256
#define IN_SZ 320          // LAT + FCON
#define HID   512
#define E_    8
#define GH    64
#define INTER 576          // LAT + HID
#define OUT_SZ 512
#define NTOT  4096         // E_ * 512
#define KI0   10           // IN_SZ/32
#define KI12  18           // INTER/32

typedef __attribute__((ext_vector_type(8))) __bf16 bf16x8;
typedef __attribute__((ext_vector_type(4))) float  f32x4;

__device__ __forceinline__ float elu_f(float x) { return x > 0.f ? x : expf(x) - 1.f; }
__device__ __forceinline__ __bf16 to_bf16(float f) {
    __hip_bfloat16 h = __float2bfloat16(f);
    return *reinterpret_cast<__bf16*>(&h);
}

// ---------------------------------------------------------------------------
// Fragment layout (mfma_f32_16x16x32_bf16 A/B operand, m89-verified):
//   frag(t0,k0)[lane][j] = X[t0 + (lane&15)][k0 + (lane>>4)*8 + j],  j=0..7
// Packed storage: buf[(tile_idx*KI + ki)*64 + lane] : bf16x8 (16 B/lane).
// ---------------------------------------------------------------------------

// ----- fused prep kernel: zcpack + 3x wpack + gate in ONE dispatch ---------
#define PREP_ZC   160
#define PREP_W0   (PREP_ZC + KI0 * 64)      // 800
#define PREP_W1   (PREP_W0 + KI12 * 64)     // 1952
#define PREP_W2   (PREP_W1 + KI12 * 64)     // 3104
#define PREP_ALL  (PREP_W2 + 256)           // 3360

__device__ __forceinline__ void do_zcpack(
    int bx, const float* __restrict__ z, const float* __restrict__ c,
    bf16x8* __restrict__ Ap0, bf16x8* __restrict__ Ap1, bf16x8* __restrict__ Ap2)
{
    const int wid  = bx * 4 + (threadIdx.x >> 6);
    const int lane = threadIdx.x & 63, q = lane >> 4, r = lane & 15;
    bf16x8 v;
    if (wid < 128) {                       // z fragment: mi in [0,64), ki in {0,1}
        const int mi = wid >> 1, ki = wid & 1;
        const float* src = z + (size_t)(mi * 16 + r) * LAT + ki * 32 + q * 8;
        const f32x4 lo = *(const f32x4*)src, hi = *(const f32x4*)(src + 4);
#pragma unroll
        for (int j = 0; j < 4; j++) { v[j] = to_bf16(lo[j]); v[j + 4] = to_bf16(hi[j]); }
        Ap0[((size_t)mi * KI0  + ki) * 64 + lane] = v;
        Ap1[((size_t)mi * KI12 + ki) * 64 + lane] = v;
        Ap2[((size_t)mi * KI12 + ki) * 64 + lane] = v;
    } else {                               // c fragment: ki in [2,10)
        const int cid = wid - 128;
        const int mi = cid >> 3, ki = 2 + (cid & 7);
        const float* src = c + (size_t)(mi * 16 + r) * FCON + (ki - 2) * 32 + q * 8;
        const f32x4 lo = *(const f32x4*)src, hi = *(const f32x4*)(src + 4);
#pragma unroll
        for (int j = 0; j < 4; j++) { v[j] = to_bf16(lo[j]); v[j + 4] = to_bf16(hi[j]); }
        Ap0[((size_t)mi * KI0 + ki) * 64 + lane] = v;
    }
}

__device__ __forceinline__ void do_wpack(
    int f, const float* __restrict__ w, bf16x8* __restrict__ Wp, int KI)
{
    const int ki = f % KI;
    const int ni = (f / KI) * 4 + (threadIdx.x >> 6);
    const int lane = threadIdx.x & 63, q = lane >> 4, r = lane & 15;
    const int n = ni * 16 + r, e = n >> 9, o = n & 511;
    const int K = KI * 32;
    const float* src = w + (size_t)e * K * 512 + (size_t)(ki * 32 + q * 8) * 512 + o;
    bf16x8 v;
#pragma unroll
    for (int j = 0; j < 8; j++) v[j] = to_bf16(src[(size_t)j * 512]);
    Wp[((size_t)ni * KI + ki) * 64 + lane] = v;
}

__global__ __launch_bounds__(256) void prep_kernel(
    const float* __restrict__ z, const float* __restrict__ c,
    const float* __restrict__ w0, const float* __restrict__ w1,
    const float* __restrict__ w2,
    const float* __restrict__ gw1, const float* __restrict__ gb1,
    const float* __restrict__ gw2, const float* __restrict__ gb2,
    const float* __restrict__ gw3, const float* __restrict__ gb3,
    bf16x8* __restrict__ Ap0, bf16x8* __restrict__ Ap1, bf16x8* __restrict__ Ap2,
    bf16x8* __restrict__ Wp0, bf16x8* __restrict__ Wp1, bf16x8* __restrict__ Wp2,
    float* __restrict__ coeff)
{
    const int bx = blockIdx.x;
    if (bx < PREP_ZC) {
        do_zcpack(bx, z, c, Ap0, Ap1, Ap2);
    } else if (bx < PREP_W0) {
        do_wpack(bx - PREP_ZC, w0, Wp0, KI0);
    } else if (bx < PREP_W1) {
        do_wpack(bx - PREP_W0, w1, Wp1, KI12);
    } else if (bx < PREP_W2) {
        do_wpack(bx - PREP_W1, w2, Wp2, KI12);
    } else {
        // ----- gate: coeff = softmax(elu(elu(x@gw1+gb1)@gw2+gb2)@gw3+gb3) ---
        __shared__ float h[4][GH];
        __shared__ float lg[4][E_];
        const int lane = threadIdx.x & 63, wave = threadIdx.x >> 6;
        const int row = (bx - PREP_W2) * 4 + wave;
        const float* zr = z + (size_t)row * LAT;
        const float* cr = c + (size_t)row * FCON;

        float a1 = gb1[lane];
        for (int i = 0; i < LAT; i++)  a1 = fmaf(zr[i], gw1[i * GH + lane], a1);
        for (int i = 0; i < FCON; i++) a1 = fmaf(cr[i], gw1[(LAT + i) * GH + lane], a1);
        h[wave][lane] = elu_f(a1);
        __syncthreads();

        float a2 = gb2[lane];
        for (int i = 0; i < GH; i++) a2 = fmaf(h[wave][i], gw2[i * GH + lane], a2);
        a2 = elu_f(a2);
        __syncthreads();
        h[wave][lane] = a2;
        __syncthreads();

        if (lane < E_) {
            float a3 = gb3[lane];
            for (int i = 0; i < GH; i++) a3 = fmaf(h[wave][i], gw3[i * E_ + lane], a3);
            lg[wave][lane] = a3;
        }
        __syncthreads();
        if (lane < E_) {
            float mx = lg[wave][0];
            for (int i = 1; i < E_; i++) mx = fmaxf(mx, lg[wave][i]);
            float s = 0.f;
            for (int i = 0; i < E_; i++) s += expf(lg[wave][i] - mx);
            coeff[(size_t)row * E_ + lane] = expf(lg[wave][lane] - mx) / s;
        }
    }
}

// ---------------------------------------------------------------------------
// Fused layer kernel, v2: 2 m-tiles per wave for 1.8x better bytes/MFMA.
// Block = 128 rows x (8 experts x 16 o-cols); wave w owns m-tiles
// mb*8 + 2w + {0,1}; all 8 expert b-frags in-register, reused for both
// a-frags (16 MFMA per 10 KB loaded vs 8 per 9 KB in v1).
// Epilogue: s = sum_e coeff[m,e]*(acc[e]+bias[e,o]) in-register, ELU+pack
// (layers 0,1) or f32 store (layer 2). grid (32 o-tiles, 8 m-blocks) = 256.
// ---------------------------------------------------------------------------
template<int KI, int FINAL>
__global__ __launch_bounds__(256) void layer_kernel(
    const bf16x8* __restrict__ Ap, const bf16x8* __restrict__ Wp,
    const float* __restrict__ coeff, const float* __restrict__ bias,
    __bf16* __restrict__ ApN, float* __restrict__ fout)
{
    const int lane = threadIdx.x & 63, w = threadIdx.x >> 6;
    const int q = lane >> 4, r = lane & 15;
    const int o0 = blockIdx.x * 16;
    const int nt = blockIdx.x;             // o-tile index within each expert
    const int mi0 = blockIdx.y * 8 + w * 2;  // first of this wave's 2 m-tiles

    const bf16x8* aB0 = Ap + (size_t)(mi0 + 0) * KI * 64 + lane;
    const bf16x8* aB1 = Ap + (size_t)(mi0 + 1) * KI * 64 + lane;
    const bf16x8* bBase = Wp + (size_t)nt * KI * 64 + lane;  // + e*(32*KI*64)

    f32x4 acc[2][E_];
#pragma unroll
    for (int u = 0; u < 2; u++)
#pragma unroll
        for (int e = 0; e < E_; e++) acc[u][e] = (f32x4){0.f, 0.f, 0.f, 0.f};

#pragma unroll
    for (int ki = 0; ki < KI; ++ki) {
        const bf16x8 af0 = aB0[(size_t)ki * 64];
        const bf16x8 af1 = aB1[(size_t)ki * 64];
        bf16x8 bf[E_];
#pragma unroll
        for (int e = 0; e < E_; e++)
            bf[e] = bBase[((size_t)e * 32 * KI + ki) * 64];
#pragma unroll
        for (int e = 0; e < E_; e++) {
            acc[0][e] = __builtin_amdgcn_mfma_f32_16x16x32_bf16(af0, bf[e], acc[0][e], 0, 0, 0);
            acc[1][e] = __builtin_amdgcn_mfma_f32_16x16x32_bf16(af1, bf[e], acc[1][e], 0, 0, 0);
        }
    }

    // bias[e, o0+r]
    float be[E_];
#pragma unroll
    for (int e = 0; e < E_; e++) be[e] = bias[(size_t)e * 512 + o0 + r];

    // D layout: col(o) = lane&15, row(m) = q*4 + v  [m89-verified]
#pragma unroll
    for (int u = 0; u < 2; u++) {
        const int mi = mi0 + u;
#pragma unroll
        for (int v = 0; v < 4; v++) {
            const int row = mi * 16 + q * 4 + v;
            const float* cr = coeff + (size_t)row * E_;
            const f32x4 clo = *(const f32x4*)cr, chi = *(const f32x4*)(cr + 4);
            float s = 0.f;
#pragma unroll
            for (int e = 0; e < 4; e++) s += clo[e] * (acc[u][e][v] + be[e]);
#pragma unroll
            for (int e = 0; e < 4; e++) s += chi[e] * (acc[u][4 + e][v] + be[4 + e]);
            if (FINAL) {
                fout[(size_t)row * OUT_SZ + o0 + r] = s;
            } else {
                const float h = elu_f(s);
                const int k  = LAT + o0 + r;           // 64..575
                const int ki2 = k >> 5, kq2 = (k & 31) >> 3, jb2 = k & 7;
                ApN[(((size_t)mi * KI12 + ki2) * 64 + kq2 * 16 + (q * 4 + v)) * 8 + jb2] =
                    to_bf16(h);
            }
        }
    }
}

// ---------------------------------------------------------------------------
static inline size_t align256(size_t x) { return (x + 255) & ~(size_t)255; }

extern "C" void kernel_launch(void* const* d_in, const int* in_sizes, int n_in,
                              void* d_out, int out_size, void* d_ws, size_t ws_size,
                              hipStream_t stream)
{
    const float* z   = (const float*)d_in[0];
    const float* c   = (const float*)d_in[1];
    const float* w0  = (const float*)d_in[2];
    const float* b0  = (const float*)d_in[3];
    const float* w1  = (const float*)d_in[4];
    const float* b1  = (const float*)d_in[5];
    const float* w2  = (const float*)d_in[6];
    const float* b2  = (const float*)d_in[7];
    const float* gw1 = (const float*)d_in[8];
    const float* gb1 = (const float*)d_in[9];
    const float* gw2 = (const float*)d_in[10];
    const float* gb2 = (const float*)d_in[11];
    const float* gw3 = (const float*)d_in[12];
    const float* gb3 = (const float*)d_in[13];
    float* out = (float*)d_out;

    uint8_t* p = (uint8_t*)d_ws;
    bf16x8* Wp0 = (bf16x8*)p; p += align256((size_t)NTOT * IN_SZ * 2);
    bf16x8* Wp1 = (bf16x8*)p; p += align256((size_t)NTOT * INTER * 2);
    bf16x8* Wp2 = (bf16x8*)p; p += align256((size_t)NTOT * INTER * 2);
    bf16x8* Ap0 = (bf16x8*)p; p += align256((size_t)B_ * IN_SZ * 2);
    bf16x8* Ap1 = (bf16x8*)p; p += align256((size_t)B_ * INTER * 2);
    bf16x8* Ap2 = (bf16x8*)p; p += align256((size_t)B_ * INTER * 2);
    float* coeff = (float*)p; p += align256((size_t)B_ * E_ * 4);

    // 1) fused prep: packs + gate (verified in R4/R6)
    prep_kernel<<<PREP_ALL, 256, 0, stream>>>(
        z, c, w0, w1, w2, gw1, gb1, gw2, gb2, gw3, gb3,
        Ap0, Ap1, Ap2, Wp0, Wp1, Wp2, coeff);

    // 2) three fused GEMM+reduce layers (no Y materialization, 2 m-tiles/wave)
    layer_kernel<KI0, 0><<<dim3(32, 8), 256, 0, stream>>>(
        Ap0, Wp0, coeff, b0, (__bf16*)Ap1, nullptr);
    layer_kernel<KI12, 0><<<dim3(32, 8), 256, 0, stream>>>(
        Ap1, Wp1, coeff, b1, (__bf16*)Ap2, nullptr);
    layer_kernel<KI12, 1><<<dim3(32, 8), 256, 0, stream>>>(
        Ap2, Wp2, coeff, b2, nullptr, out);
}